// Round 3
// baseline (1425.715 us; speedup 1.0000x reference)
//
#include <hip/hip_runtime.h>

typedef __bf16 bf16x8 __attribute__((ext_vector_type(8)));
typedef float f32x4 __attribute__((ext_vector_type(4)));
typedef unsigned short u16;
typedef unsigned int u32;
typedef unsigned long long u64;

#define NF_ 133
#define EF_ 14
#define HD 300
#define KH 320   // padded K for h GEMMs (10 ksteps of 32)
#define K0 160   // padded K for h0 GEMM (133+14 -> 160)
#define K2 448   // padded K for node GEMM (133 vv | 3 gap | 300 m_v | pad)
#define NT 19    // n tiles of 16 covering 300 (pad 304)
#define SHP 2432 // shT row pitch in u16 (304 cols * 8)

__device__ __forceinline__ u16 f2bf(float f) {
    union { float f; u32 u; } v; v.f = f;
    u32 r = v.u + 0x7fffu + ((v.u >> 16) & 1u);
    return (u16)(r >> 16);
}
__device__ __forceinline__ float bf2f(u16 h) {
    union { u32 u; float f; } v; v.u = ((u32)h) << 16;
    return v.f;
}

// ---------- prep: W[K][N] fp32 -> Wt[NP][KP] bf16 (N-major, zero padded) ----------
// gap=1: source row remap k<133 -> k ; 136<=k<436 -> k-3 ; else zero (for Wa alignment gap)
__global__ void prep_w(const float* __restrict__ W, u16* __restrict__ Wt,
                       int K, int N, int KP, int NP, int gap) {
    int idx = blockIdx.x * 256 + threadIdx.x;
    if (idx >= NP * KP) return;
    int n = idx / KP, k = idx - n * KP;
    int kk = k;
    if (gap) kk = (k < 133) ? k : ((k >= 136 && k < 436) ? k - 3 : -1);
    float val = (kk >= 0 && kk < K && n < N) ? W[kk * N + n] : 0.f;
    Wt[idx] = f2bf(val);
}

// ---------- prep: globals -> Ar1 cols [300,512) ----------
__global__ void prep_glob(const float* __restrict__ glob, u16* __restrict__ Ar1) {
    int idx = blockIdx.x * 256 + threadIdx.x;
    if (idx >= 4096 * 212) return;
    int g = idx / 212, c = 300 + (idx - g * 212);
    float val = (c < 500) ? glob[g * 200 + (c - 300)] : 0.f;
    Ar1[g * 512 + c] = f2bf(val);
}

// ---------- mega kernel: one block (512 thr) per graph, 2 blocks/CU ----------
// A-operand LDS layout (rows R, cols K): elem(r,c) = (c/8)*(R*8) + r*8 + (c%8)
// B-operand (hT)   layout: elem(c,k) = (k/8)*SHP + c*8 + (k%8)
__global__ __launch_bounds__(512, 4) void gnn_mega(
    const float* __restrict__ vf, const float* __restrict__ ef,
    const int* __restrict__ src, const int* __restrict__ dst,
    const u16* __restrict__ WiT, const u16* __restrict__ WmT, const u16* __restrict__ WaT,
    const float* __restrict__ bi, const float* __restrict__ bm, const float* __restrict__ ba,
    u16* __restrict__ Ar1)
{
    __shared__ u16 sm[64 * KH];     // 40960 B : A0 / m (R=64) ; later A2 (R=32)
    __shared__ u16 shT[8 * SHP];    // 38912 B : hT (B-layout)
    __shared__ u64 s_amask[32];     // per-node in-edge bitmask over k
    __shared__ u64 s_smask[32];     // per-node out-edge bitmask over k
    __shared__ int s_src[64];
    __shared__ unsigned char s_src8[64];

    const int g = blockIdx.x;
    const int tid = threadIdx.x;
    const int wave = tid >> 6;
    const int lane = tid & 63;
    const int lm = lane & 15;
    const int q = lane >> 4;

    if (tid < 64) {
        int sv = src[g * 64 + tid] - g * 32;
        int dv = dst[g * 64 + tid] - g * 32;
        s_src[tid] = sv;
        s_src8[tid] = (unsigned char)sv;
        #pragma unroll 1
        for (int n = 0; n < 32; ++n) {
            u64 bmA = __ballot(dv == n);
            u64 bmS = __ballot(sv == n);
            if (tid == 0) { s_amask[n] = bmA; s_smask[n] = bmS; }
        }
    }
    // zero shT fully (cols 300..303 must stay 0); zero sm chunks 38,39 (c 304..319)
    for (int i = tid; i < 9728; i += 512) ((u32*)shT)[i] = 0u;
    if (tid < 512) ((u32*)sm)[9728 + tid] = 0u;
    __syncthreads();

    // build A0 = [vv[src[e]] | ee | 0] (64 x 160), c-fastest for coalescing
    for (int idx = tid; idx < 64 * K0; idx += 512) {
        int ed = idx / K0, c = idx - ed * K0;
        float val = 0.f;
        if (c < NF_) val = vf[(size_t)(g * 32 + s_src[ed]) * (NF_ + 1) + c];
        else if (c < NF_ + EF_) val = ef[(size_t)(g * 64 + ed) * (EF_ + 1) + (c - NF_)];
        sm[((c >> 3) << 9) + (ed << 3) + (c & 7)] = f2bf(val);
    }
    __syncthreads();

    // ---------------- h0 GEMM: (64x160) @ WiT -> h0 (bf16-packed regs) + shT ----------------
    u64 h0p[3][4];
    float bmv[3];
    {
        f32x4 acc[3][4];
        #pragma unroll
        for (int t = 0; t < 3; ++t)
            #pragma unroll
            for (int mt = 0; mt < 4; ++mt) acc[t][mt] = (f32x4){0.f, 0.f, 0.f, 0.f};
        #pragma unroll
        for (int ks = 0; ks < 5; ++ks) {
            bf16x8 af[4];
            #pragma unroll
            for (int mt = 0; mt < 4; ++mt)
                af[mt] = *(const bf16x8*)&sm[((ks * 4 + q) << 9) + ((mt * 16 + lm) << 3)];
            #pragma unroll
            for (int t = 0; t < 3; ++t) {
                int j = 8 * t + wave;
                if (j < NT) {
                    bf16x8 bfr = *(const bf16x8*)&WiT[(j * 16 + lm) * K0 + ks * 32 + q * 8];
                    #pragma unroll
                    for (int mt = 0; mt < 4; ++mt)
                        acc[t][mt] = __builtin_amdgcn_mfma_f32_16x16x32_bf16(af[mt], bfr, acc[t][mt], 0, 0, 0);
                }
            }
        }
        #pragma unroll
        for (int t = 0; t < 3; ++t) {
            int j = 8 * t + wave;
            int n = j * 16 + lm;
            bool ok = (j < NT) && (n < HD);
            float bv = ok ? bi[n] : 0.f;
            bmv[t] = ok ? bm[n] : 0.f;
            #pragma unroll
            for (int mt = 0; mt < 4; ++mt) {
                u64 w = 0;
                #pragma unroll
                for (int r = 0; r < 4; ++r) {
                    float hv = acc[t][mt][r] + bv;
                    hv = hv > 0.f ? hv : 0.f;
                    w |= ((u64)f2bf(hv)) << (16 * r);
                }
                h0p[t][mt] = w;
                if (ok) *(u64*)&shT[(mt * 2 + (q >> 1)) * SHP + n * 8 + (q & 1) * 4] = w;
            }
        }
    }

    // ---------------- 3 message-passing layers, all-MFMA ----------------
    for (int layer = 0; layer < 3; ++layer) {
        __syncthreads();
        // GEMM1': mT[c][e] = sum_k h[k][c] * A_e[e][k]  (A = hT frags, B = mask-synth frags)
        {
            // per-lane A_e column masks (recomputed per layer to keep regs scoped)
            u64 am[4];
            #pragma unroll
            for (int mt = 0; mt < 4; ++mt) {
                int e = mt * 16 + lm;
                am[mt] = s_amask[s_src8[e]] & ~(1ull << (e ^ 1));
            }
            bf16x8 bfrag[2][4];
            #pragma unroll
            for (int ks = 0; ks < 2; ++ks) {
                int kb = ks * 32 + q * 8;
                #pragma unroll
                for (int mt = 0; mt < 4; ++mt) {
                    union { u32 w[4]; bf16x8 v; } fb;
                    #pragma unroll
                    for (int jj = 0; jj < 4; ++jj) {
                        u32 lo = (u32)((am[mt] >> (kb + 2 * jj)) & 1ull) * 0x3F80u;
                        u32 hi = (u32)((am[mt] >> (kb + 2 * jj + 1)) & 1ull) * 0x3F80u;
                        fb.w[jj] = lo | (hi << 16);
                    }
                    bfrag[ks][mt] = fb.v;
                }
            }
            #pragma unroll
            for (int t = 0; t < 3; ++t) {
                int j = 8 * t + wave;
                if (j < NT) {
                    f32x4 mac[4];
                    #pragma unroll
                    for (int mt = 0; mt < 4; ++mt) mac[mt] = (f32x4){0.f, 0.f, 0.f, 0.f};
                    #pragma unroll
                    for (int ks = 0; ks < 2; ++ks) {
                        bf16x8 af = *(const bf16x8*)&shT[(ks * 4 + q) * SHP + (j * 16 + lm) * 8];
                        #pragma unroll
                        for (int mt = 0; mt < 4; ++mt)
                            mac[mt] = __builtin_amdgcn_mfma_f32_16x16x32_bf16(af, bfrag[ks][mt], mac[mt], 0, 0, 0);
                    }
                    // write m into sm A-layout: elem(e,c), c = j*16+q*4+r -> u64 over r
                    #pragma unroll
                    for (int mt = 0; mt < 4; ++mt) {
                        u64 w = 0;
                        #pragma unroll
                        for (int r = 0; r < 4; ++r) w |= ((u64)f2bf(mac[mt][r])) << (16 * r);
                        *(u64*)&sm[(j * 2 + (q >> 1)) * 512 + (mt * 16 + lm) * 8 + (q & 1) * 4] = w;
                    }
                }
            }
        }
        __syncthreads();
        // GEMM2: h = relu(h0 + m @ Wm + bm) -> shT
        {
            f32x4 acc[3][4];
            #pragma unroll
            for (int t = 0; t < 3; ++t)
                #pragma unroll
                for (int mt = 0; mt < 4; ++mt) acc[t][mt] = (f32x4){0.f, 0.f, 0.f, 0.f};
            #pragma unroll
            for (int ks = 0; ks < 10; ++ks) {
                bf16x8 af[4];
                #pragma unroll
                for (int mt = 0; mt < 4; ++mt)
                    af[mt] = *(const bf16x8*)&sm[((ks * 4 + q) << 9) + ((mt * 16 + lm) << 3)];
                #pragma unroll
                for (int t = 0; t < 3; ++t) {
                    int j = 8 * t + wave;
                    if (j < NT) {
                        bf16x8 bfr = *(const bf16x8*)&WmT[(j * 16 + lm) * KH + ks * 32 + q * 8];
                        #pragma unroll
                        for (int mt = 0; mt < 4; ++mt)
                            acc[t][mt] = __builtin_amdgcn_mfma_f32_16x16x32_bf16(af[mt], bfr, acc[t][mt], 0, 0, 0);
                    }
                }
            }
            #pragma unroll
            for (int t = 0; t < 3; ++t) {
                int j = 8 * t + wave;
                int n = j * 16 + lm;
                bool ok = (j < NT) && (n < HD);
                #pragma unroll
                for (int mt = 0; mt < 4; ++mt) {
                    u64 w = 0;
                    #pragma unroll
                    for (int r = 0; r < 4; ++r) {
                        float h0v = bf2f((u16)(h0p[t][mt] >> (16 * r)));
                        float hv = h0v + acc[t][mt][r] + bmv[t];
                        hv = hv > 0.f ? hv : 0.f;
                        w |= ((u64)f2bf(hv)) << (16 * r);
                    }
                    if (ok) *(u64*)&shT[(mt * 2 + (q >> 1)) * SHP + n * 8 + (q & 1) * 4] = w;
                }
            }
        }
    }
    __syncthreads();

    // ---- A2 vv part + zeros (32 x 448, A-layout R=32) into sm ----
    for (int idx = tid; idx < 32 * K2; idx += 512) {
        int n = idx / K2, c = idx - n * K2;
        float val = (c < NF_) ? vf[(size_t)(g * 32 + n) * (NF_ + 1) + c] : 0.f;
        sm[((c >> 3) << 8) + (n << 3) + (c & 7)] = f2bf(val);
    }
    __syncthreads();

    // ---- m_vT[c][n] = sum_k h[k][c] * S_out[n][k] -> sm cols 136..435 ----
    {
        bf16x8 sfrag[2][2];
        #pragma unroll
        for (int ks = 0; ks < 2; ++ks) {
            int kb = ks * 32 + q * 8;
            #pragma unroll
            for (int mt = 0; mt < 2; ++mt) {
                u64 msk = s_smask[mt * 16 + lm];
                union { u32 w[4]; bf16x8 v; } fb;
                #pragma unroll
                for (int jj = 0; jj < 4; ++jj) {
                    u32 lo = (u32)((msk >> (kb + 2 * jj)) & 1ull) * 0x3F80u;
                    u32 hi = (u32)((msk >> (kb + 2 * jj + 1)) & 1ull) * 0x3F80u;
                    fb.w[jj] = lo | (hi << 16);
                }
                sfrag[ks][mt] = fb.v;
            }
        }
        #pragma unroll
        for (int t = 0; t < 3; ++t) {
            int j = 8 * t + wave;
            if (j < NT) {
                f32x4 vacc[2];
                #pragma unroll
                for (int mt = 0; mt < 2; ++mt) vacc[mt] = (f32x4){0.f, 0.f, 0.f, 0.f};
                #pragma unroll
                for (int ks = 0; ks < 2; ++ks) {
                    bf16x8 af = *(const bf16x8*)&shT[(ks * 4 + q) * SHP + (j * 16 + lm) * 8];
                    #pragma unroll
                    for (int mt = 0; mt < 2; ++mt)
                        vacc[mt] = __builtin_amdgcn_mfma_f32_16x16x32_bf16(af, sfrag[ks][mt], vacc[mt], 0, 0, 0);
                }
                // write at cc = 136 + j*16 + q*4 + r  (136 = 17*8 keeps u64 alignment)
                #pragma unroll
                for (int mt = 0; mt < 2; ++mt) {
                    u64 w = 0;
                    #pragma unroll
                    for (int r = 0; r < 4; ++r) w |= ((u64)f2bf(vacc[mt][r])) << (16 * r);
                    *(u64*)&sm[(17 + j * 2 + (q >> 1)) * 256 + (mt * 16 + lm) * 8 + (q & 1) * 4] = w;
                }
            }
        }
    }
    __syncthreads();

    // ---- h_v = relu(A2 @ Wa + ba); mean over 32 nodes -> Ar1[g][0:300] ----
    {
        f32x4 acc2[3][2];
        #pragma unroll
        for (int t = 0; t < 3; ++t)
            #pragma unroll
            for (int mt = 0; mt < 2; ++mt) acc2[t][mt] = (f32x4){0.f, 0.f, 0.f, 0.f};
        #pragma unroll
        for (int ks = 0; ks < 14; ++ks) {
            bf16x8 af[2];
            #pragma unroll
            for (int mt = 0; mt < 2; ++mt)
                af[mt] = *(const bf16x8*)&sm[((ks * 4 + q) << 8) + ((mt * 16 + lm) << 3)];
            #pragma unroll
            for (int t = 0; t < 3; ++t) {
                int j = 8 * t + wave;
                if (j < NT) {
                    bf16x8 bfr = *(const bf16x8*)&WaT[(j * 16 + lm) * K2 + ks * 32 + q * 8];
                    #pragma unroll
                    for (int mt = 0; mt < 2; ++mt)
                        acc2[t][mt] = __builtin_amdgcn_mfma_f32_16x16x32_bf16(af[mt], bfr, acc2[t][mt], 0, 0, 0);
                }
            }
        }
        #pragma unroll
        for (int t = 0; t < 3; ++t) {
            int j = 8 * t + wave;
            int n = j * 16 + lm;
            bool ok = (j < NT) && (n < HD);
            float bav = ok ? ba[n] : 0.f;
            float s = 0.f;
            #pragma unroll
            for (int mt = 0; mt < 2; ++mt)
                #pragma unroll
                for (int r = 0; r < 4; ++r) {
                    float hv = acc2[t][mt][r] + bav;
                    s += (hv > 0.f ? hv : 0.f);
                }
            s += __shfl_xor(s, 16);
            s += __shfl_xor(s, 32);
            if (ok && q == 0) Ar1[g * 512 + n] = f2bf(s * 0.03125f);
        }
    }
}

// ---------- generic LDS-free readout GEMM: C = [relu](A @ Bt^T + bias) ----------
template<int RELU, int OUTBF16>
__global__ __launch_bounds__(256, 4) void gemm_ro(
    const u16* __restrict__ A, const u16* __restrict__ Bt, const float* __restrict__ bias,
    const int KP, const int Nreal, const int outPitch, void* __restrict__ outp, const int nsteps)
{
    const int tid = threadIdx.x;
    const int wv = tid >> 6, lane = tid & 63, lm = lane & 15, q = lane >> 4;
    const int row0 = blockIdx.x * 64;
    const int col = blockIdx.y * 64 + wv * 16 + lm;
    f32x4 acc[4];
    #pragma unroll
    for (int mt = 0; mt < 4; ++mt) acc[mt] = (f32x4){0.f, 0.f, 0.f, 0.f};
    const u16* bp = Bt + col * KP + q * 8;
    const u16* ap = A + (row0 + lm) * KP + q * 8;
    for (int ks = 0; ks < nsteps; ++ks) {
        bf16x8 bfr = *(const bf16x8*)(bp + ks * 32);
        #pragma unroll
        for (int mt = 0; mt < 4; ++mt) {
            bf16x8 afr = *(const bf16x8*)(ap + mt * 16 * KP + ks * 32);
            acc[mt] = __builtin_amdgcn_mfma_f32_16x16x32_bf16(afr, bfr, acc[mt], 0, 0, 0);
        }
    }
    const float bv = (col < Nreal) ? bias[col] : 0.f;
    #pragma unroll
    for (int mt = 0; mt < 4; ++mt) {
        #pragma unroll
        for (int r = 0; r < 4; ++r) {
            int row = row0 + mt * 16 + q * 4 + r;
            float val = acc[mt][r] + bv;
            if (RELU) val = val > 0.f ? val : 0.f;
            if (OUTBF16) {
                ((u16*)outp)[row * outPitch + col] = (col < Nreal) ? f2bf(val) : (u16)0;
            } else {
                if (col < Nreal) ((float*)outp)[row * outPitch + col] = val;
            }
        }
    }
}

extern "C" void kernel_launch(void* const* d_in, const int* in_sizes, int n_in,
                              void* d_out, int out_size, void* d_ws, size_t ws_size,
                              hipStream_t stream) {
    (void)in_sizes; (void)n_in; (void)out_size; (void)ws_size;
    const float* v   = (const float*)d_in[0];
    const float* e   = (const float*)d_in[1];
    const float* glb = (const float*)d_in[2];
    const float* Wi  = (const float*)d_in[3];
    const float* bi  = (const float*)d_in[4];
    const float* Wm  = (const float*)d_in[5];
    const float* bm  = (const float*)d_in[6];
    const float* Wa  = (const float*)d_in[7];
    const float* ba  = (const float*)d_in[8];
    const float* Wr1 = (const float*)d_in[9];
    const float* br1 = (const float*)d_in[10];
    const float* Wr2 = (const float*)d_in[11];
    const float* br2 = (const float*)d_in[12];
    const float* Wr3 = (const float*)d_in[13];
    const float* br3 = (const float*)d_in[14];
    const int* src = (const int*)d_in[15];
    const int* dst = (const int*)d_in[16];

    char* ws = (char*)d_ws;
    u16* WiT  = (u16*)(ws + 0);            // 304*160*2  =   97280
    u16* WmT  = (u16*)(ws + 97280);        // 304*320*2  =  194560
    u16* WaT  = (u16*)(ws + 291840);       // 304*448*2  =  272384
    u16* Wr1T = (u16*)(ws + 564224);       // 576*512*2  =  589824
    u16* Wr2T = (u16*)(ws + 1154048);      // 384*576*2  =  442368
    u16* Wr3T = (u16*)(ws + 1596416);      //  64*384*2  =   49152
    u16* Ar1  = (u16*)(ws + 1645568);      // 4096*512*2 = 4194304
    u16* Ar2  = (u16*)(ws + 5839872);      // 4096*576*2 = 4718592
    u16* Ar3  = (u16*)(ws + 10558464);     // 4096*384*2 = 3145728

    prep_w<<<190,  256, 0, stream>>>(Wi,  WiT,  147, 300, 160, 304, 0);
    prep_w<<<380,  256, 0, stream>>>(Wm,  WmT,  300, 300, 320, 304, 0);
    prep_w<<<532,  256, 0, stream>>>(Wa,  WaT,  433, 300, 448, 304, 1);
    prep_w<<<1152, 256, 0, stream>>>(Wr1, Wr1T, 500, 550, 512, 576, 0);
    prep_w<<<864,  256, 0, stream>>>(Wr2, Wr2T, 550, 378, 576, 384, 0);
    prep_w<<<96,   256, 0, stream>>>(Wr3, Wr3T, 378, 12,  384, 64,  0);
    prep_glob<<<3392, 256, 0, stream>>>(glb, Ar1);

    gnn_mega<<<4096, 512, 0, stream>>>(v, e, src, dst, WiT, WmT, WaT, bi, bm, ba, Ar1);

    gemm_ro<1, 1><<<dim3(64, 9), 256, 0, stream>>>(Ar1, Wr1T, br1, 512, 550, 576, Ar2, 16);
    gemm_ro<1, 1><<<dim3(64, 6), 256, 0, stream>>>(Ar2, Wr2T, br2, 576, 378, 384, Ar3, 18);
    gemm_ro<0, 0><<<dim3(64, 1), 256, 0, stream>>>(Ar3, Wr3T, br3, 384, 12, 12, d_out, 12);
}

// Round 4
// 1001.318 us; speedup vs baseline: 1.4238x; 1.4238x over previous
//
#include <hip/hip_runtime.h>

typedef __bf16 bf16x8 __attribute__((ext_vector_type(8)));
typedef float f32x4 __attribute__((ext_vector_type(4)));
typedef unsigned short u16;
typedef unsigned int u32;
typedef unsigned long long u64;

#define NF_ 133
#define EF_ 14
#define HD 300
#define KH 320   // padded K for h GEMMs (10 ksteps of 32)
#define K0 160   // padded K for h0 GEMM (133+14 -> 160)
#define K2 448   // padded K for node GEMM (133 vv | 3 gap | 300 m_v | pad)
#define NT 19    // n tiles of 16 covering 300 (pad 304)
#define SHP 2432 // shT row pitch in u16 (304 cols * 8)

__device__ __forceinline__ u16 f2bf(float f) {
    union { float f; u32 u; } v; v.f = f;
    u32 r = v.u + 0x7fffu + ((v.u >> 16) & 1u);
    return (u16)(r >> 16);
}
__device__ __forceinline__ float bf2f(u16 h) {
    union { u32 u; float f; } v; v.u = ((u32)h) << 16;
    return v.f;
}

// ---------- prep: W[K][N] fp32 -> Wt[NP][KP] bf16 (N-major, zero padded) ----------
// gap=1: source row remap k<133 -> k ; 136<=k<436 -> k-3 ; else zero (for Wa alignment gap)
__global__ void prep_w(const float* __restrict__ W, u16* __restrict__ Wt,
                       int K, int N, int KP, int NP, int gap) {
    int idx = blockIdx.x * 256 + threadIdx.x;
    if (idx >= NP * KP) return;
    int n = idx / KP, k = idx - n * KP;
    int kk = k;
    if (gap) kk = (k < 133) ? k : ((k >= 136 && k < 436) ? k - 3 : -1);
    float val = (kk >= 0 && kk < K && n < N) ? W[kk * N + n] : 0.f;
    Wt[idx] = f2bf(val);
}

// ---------- prep: globals -> Ar1 cols [300,512) ----------
__global__ void prep_glob(const float* __restrict__ glob, u16* __restrict__ Ar1) {
    int idx = blockIdx.x * 256 + threadIdx.x;
    if (idx >= 4096 * 212) return;
    int g = idx / 212, c = 300 + (idx - g * 212);
    float val = (c < 500) ? glob[g * 200 + (c - 300)] : 0.f;
    Ar1[g * 512 + c] = f2bf(val);
}

// ---------- mega kernel: one block (512 thr) per graph, 2 blocks/CU ----------
// NOTE: __launch_bounds__ 2nd arg behaves as min BLOCKS/CU here (measured:
// (512,4) -> 64 VGPR cap = 32 waves/CU; (512,1) -> 100 VGPR natural).
// (512,2) -> 16 waves/CU -> 128 VGPR cap, which fits the ~100-reg live set.
// A-operand LDS layout (rows R, cols K): elem(r,c) = (c/8)*(R*8) + r*8 + (c%8)
// B-operand (hT)   layout: elem(c,k) = (k/8)*SHP + c*8 + (k%8)
__global__ __launch_bounds__(512, 2) void gnn_mega(
    const float* __restrict__ vf, const float* __restrict__ ef,
    const int* __restrict__ src, const int* __restrict__ dst,
    const u16* __restrict__ WiT, const u16* __restrict__ WmT, const u16* __restrict__ WaT,
    const float* __restrict__ bi, const float* __restrict__ bm, const float* __restrict__ ba,
    u16* __restrict__ Ar1)
{
    __shared__ u16 sm[64 * KH];     // 40960 B : A0 / m (R=64) ; later A2 (R=32)
    __shared__ u16 shT[8 * SHP];    // 38912 B : hT (B-layout)
    __shared__ u64 s_amask[32];     // per-node in-edge bitmask over k
    __shared__ u64 s_smask[32];     // per-node out-edge bitmask over k
    __shared__ int s_src[64];
    __shared__ unsigned char s_src8[64];

    const int g = blockIdx.x;
    const int tid = threadIdx.x;
    const int wave = tid >> 6;
    const int lane = tid & 63;
    const int lm = lane & 15;
    const int q = lane >> 4;

    if (tid < 64) {
        int sv = src[g * 64 + tid] - g * 32;
        int dv = dst[g * 64 + tid] - g * 32;
        s_src[tid] = sv;
        s_src8[tid] = (unsigned char)sv;
        #pragma unroll 1
        for (int n = 0; n < 32; ++n) {
            u64 bmA = __ballot(dv == n);
            u64 bmS = __ballot(sv == n);
            if (tid == 0) { s_amask[n] = bmA; s_smask[n] = bmS; }
        }
    }
    // zero shT fully (cols 300..303 must stay 0); zero sm chunks 38,39 (c 304..319)
    for (int i = tid; i < 9728; i += 512) ((u32*)shT)[i] = 0u;
    if (tid < 512) ((u32*)sm)[9728 + tid] = 0u;
    __syncthreads();

    // build A0 = [vv[src[e]] | ee | 0] (64 x 160), c-fastest for coalescing
    for (int idx = tid; idx < 64 * K0; idx += 512) {
        int ed = idx / K0, c = idx - ed * K0;
        float val = 0.f;
        if (c < NF_) val = vf[(size_t)(g * 32 + s_src[ed]) * (NF_ + 1) + c];
        else if (c < NF_ + EF_) val = ef[(size_t)(g * 64 + ed) * (EF_ + 1) + (c - NF_)];
        sm[((c >> 3) << 9) + (ed << 3) + (c & 7)] = f2bf(val);
    }
    __syncthreads();

    // ---------------- h0 GEMM: (64x160) @ WiT -> h0 (bf16-packed regs) + shT ----------------
    u64 h0p[3][4];
    float bmv[3];
    {
        f32x4 acc[3][4];
        #pragma unroll
        for (int t = 0; t < 3; ++t)
            #pragma unroll
            for (int mt = 0; mt < 4; ++mt) acc[t][mt] = (f32x4){0.f, 0.f, 0.f, 0.f};
        #pragma unroll
        for (int ks = 0; ks < 5; ++ks) {
            bf16x8 af[4];
            #pragma unroll
            for (int mt = 0; mt < 4; ++mt)
                af[mt] = *(const bf16x8*)&sm[((ks * 4 + q) << 9) + ((mt * 16 + lm) << 3)];
            #pragma unroll
            for (int t = 0; t < 3; ++t) {
                int j = 8 * t + wave;
                if (j < NT) {
                    bf16x8 bfr = *(const bf16x8*)&WiT[(j * 16 + lm) * K0 + ks * 32 + q * 8];
                    #pragma unroll
                    for (int mt = 0; mt < 4; ++mt)
                        acc[t][mt] = __builtin_amdgcn_mfma_f32_16x16x32_bf16(af[mt], bfr, acc[t][mt], 0, 0, 0);
                }
            }
        }
        #pragma unroll
        for (int t = 0; t < 3; ++t) {
            int j = 8 * t + wave;
            int n = j * 16 + lm;
            bool ok = (j < NT) && (n < HD);
            float bv = ok ? bi[n] : 0.f;
            bmv[t] = ok ? bm[n] : 0.f;
            #pragma unroll
            for (int mt = 0; mt < 4; ++mt) {
                u64 w = 0;
                #pragma unroll
                for (int r = 0; r < 4; ++r) {
                    float hv = acc[t][mt][r] + bv;
                    hv = hv > 0.f ? hv : 0.f;
                    w |= ((u64)f2bf(hv)) << (16 * r);
                }
                h0p[t][mt] = w;
                if (ok) *(u64*)&shT[(mt * 2 + (q >> 1)) * SHP + n * 8 + (q & 1) * 4] = w;
            }
        }
    }

    // ---------------- 3 message-passing layers, all-MFMA ----------------
    for (int layer = 0; layer < 3; ++layer) {
        __syncthreads();
        // GEMM1': mT[c][e] = sum_k h[k][c] * A_e[e][k]  (A = hT frags, B = mask-synth frags)
        {
            // per-lane A_e column masks (recomputed per layer to keep regs scoped)
            u64 am[4];
            #pragma unroll
            for (int mt = 0; mt < 4; ++mt) {
                int e = mt * 16 + lm;
                am[mt] = s_amask[s_src8[e]] & ~(1ull << (e ^ 1));
            }
            bf16x8 bfrag[2][4];
            #pragma unroll
            for (int ks = 0; ks < 2; ++ks) {
                int kb = ks * 32 + q * 8;
                #pragma unroll
                for (int mt = 0; mt < 4; ++mt) {
                    union { u32 w[4]; bf16x8 v; } fb;
                    #pragma unroll
                    for (int jj = 0; jj < 4; ++jj) {
                        u32 lo = (u32)((am[mt] >> (kb + 2 * jj)) & 1ull) * 0x3F80u;
                        u32 hi = (u32)((am[mt] >> (kb + 2 * jj + 1)) & 1ull) * 0x3F80u;
                        fb.w[jj] = lo | (hi << 16);
                    }
                    bfrag[ks][mt] = fb.v;
                }
            }
            #pragma unroll
            for (int t = 0; t < 3; ++t) {
                int j = 8 * t + wave;
                if (j < NT) {
                    f32x4 mac[4];
                    #pragma unroll
                    for (int mt = 0; mt < 4; ++mt) mac[mt] = (f32x4){0.f, 0.f, 0.f, 0.f};
                    #pragma unroll
                    for (int ks = 0; ks < 2; ++ks) {
                        bf16x8 af = *(const bf16x8*)&shT[(ks * 4 + q) * SHP + (j * 16 + lm) * 8];
                        #pragma unroll
                        for (int mt = 0; mt < 4; ++mt)
                            mac[mt] = __builtin_amdgcn_mfma_f32_16x16x32_bf16(af, bfrag[ks][mt], mac[mt], 0, 0, 0);
                    }
                    // write m into sm A-layout: elem(e,c), c = j*16+q*4+r -> u64 over r
                    #pragma unroll
                    for (int mt = 0; mt < 4; ++mt) {
                        u64 w = 0;
                        #pragma unroll
                        for (int r = 0; r < 4; ++r) w |= ((u64)f2bf(mac[mt][r])) << (16 * r);
                        *(u64*)&sm[(j * 2 + (q >> 1)) * 512 + (mt * 16 + lm) * 8 + (q & 1) * 4] = w;
                    }
                }
            }
        }
        __syncthreads();
        // GEMM2: h = relu(h0 + m @ Wm + bm) -> shT
        {
            f32x4 acc[3][4];
            #pragma unroll
            for (int t = 0; t < 3; ++t)
                #pragma unroll
                for (int mt = 0; mt < 4; ++mt) acc[t][mt] = (f32x4){0.f, 0.f, 0.f, 0.f};
            #pragma unroll
            for (int ks = 0; ks < 10; ++ks) {
                bf16x8 af[4];
                #pragma unroll
                for (int mt = 0; mt < 4; ++mt)
                    af[mt] = *(const bf16x8*)&sm[((ks * 4 + q) << 9) + ((mt * 16 + lm) << 3)];
                #pragma unroll
                for (int t = 0; t < 3; ++t) {
                    int j = 8 * t + wave;
                    if (j < NT) {
                        bf16x8 bfr = *(const bf16x8*)&WmT[(j * 16 + lm) * KH + ks * 32 + q * 8];
                        #pragma unroll
                        for (int mt = 0; mt < 4; ++mt)
                            acc[t][mt] = __builtin_amdgcn_mfma_f32_16x16x32_bf16(af[mt], bfr, acc[t][mt], 0, 0, 0);
                    }
                }
            }
            #pragma unroll
            for (int t = 0; t < 3; ++t) {
                int j = 8 * t + wave;
                int n = j * 16 + lm;
                bool ok = (j < NT) && (n < HD);
                #pragma unroll
                for (int mt = 0; mt < 4; ++mt) {
                    u64 w = 0;
                    #pragma unroll
                    for (int r = 0; r < 4; ++r) {
                        float h0v = bf2f((u16)(h0p[t][mt] >> (16 * r)));
                        float hv = h0v + acc[t][mt][r] + bmv[t];
                        hv = hv > 0.f ? hv : 0.f;
                        w |= ((u64)f2bf(hv)) << (16 * r);
                    }
                    if (ok) *(u64*)&shT[(mt * 2 + (q >> 1)) * SHP + n * 8 + (q & 1) * 4] = w;
                }
            }
        }
    }
    __syncthreads();

    // ---- A2 vv part + zeros (32 x 448, A-layout R=32) into sm ----
    for (int idx = tid; idx < 32 * K2; idx += 512) {
        int n = idx / K2, c = idx - n * K2;
        float val = (c < NF_) ? vf[(size_t)(g * 32 + n) * (NF_ + 1) + c] : 0.f;
        sm[((c >> 3) << 8) + (n << 3) + (c & 7)] = f2bf(val);
    }
    __syncthreads();

    // ---- m_vT[c][n] = sum_k h[k][c] * S_out[n][k] -> sm cols 136..435 ----
    {
        bf16x8 sfrag[2][2];
        #pragma unroll
        for (int ks = 0; ks < 2; ++ks) {
            int kb = ks * 32 + q * 8;
            #pragma unroll
            for (int mt = 0; mt < 2; ++mt) {
                u64 msk = s_smask[mt * 16 + lm];
                union { u32 w[4]; bf16x8 v; } fb;
                #pragma unroll
                for (int jj = 0; jj < 4; ++jj) {
                    u32 lo = (u32)((msk >> (kb + 2 * jj)) & 1ull) * 0x3F80u;
                    u32 hi = (u32)((msk >> (kb + 2 * jj + 1)) & 1ull) * 0x3F80u;
                    fb.w[jj] = lo | (hi << 16);
                }
                sfrag[ks][mt] = fb.v;
            }
        }
        #pragma unroll
        for (int t = 0; t < 3; ++t) {
            int j = 8 * t + wave;
            if (j < NT) {
                f32x4 vacc[2];
                #pragma unroll
                for (int mt = 0; mt < 2; ++mt) vacc[mt] = (f32x4){0.f, 0.f, 0.f, 0.f};
                #pragma unroll
                for (int ks = 0; ks < 2; ++ks) {
                    bf16x8 af = *(const bf16x8*)&shT[(ks * 4 + q) * SHP + (j * 16 + lm) * 8];
                    #pragma unroll
                    for (int mt = 0; mt < 2; ++mt)
                        vacc[mt] = __builtin_amdgcn_mfma_f32_16x16x32_bf16(af, sfrag[ks][mt], vacc[mt], 0, 0, 0);
                }
                // write at cc = 136 + j*16 + q*4 + r  (136 = 17*8 keeps u64 alignment)
                #pragma unroll
                for (int mt = 0; mt < 2; ++mt) {
                    u64 w = 0;
                    #pragma unroll
                    for (int r = 0; r < 4; ++r) w |= ((u64)f2bf(vacc[mt][r])) << (16 * r);
                    *(u64*)&sm[(17 + j * 2 + (q >> 1)) * 256 + (mt * 16 + lm) * 8 + (q & 1) * 4] = w;
                }
            }
        }
    }
    __syncthreads();

    // ---- h_v = relu(A2 @ Wa + ba); mean over 32 nodes -> Ar1[g][0:300] ----
    {
        f32x4 acc2[3][2];
        #pragma unroll
        for (int t = 0; t < 3; ++t)
            #pragma unroll
            for (int mt = 0; mt < 2; ++mt) acc2[t][mt] = (f32x4){0.f, 0.f, 0.f, 0.f};
        #pragma unroll
        for (int ks = 0; ks < 14; ++ks) {
            bf16x8 af[2];
            #pragma unroll
            for (int mt = 0; mt < 2; ++mt)
                af[mt] = *(const bf16x8*)&sm[((ks * 4 + q) << 8) + ((mt * 16 + lm) << 3)];
            #pragma unroll
            for (int t = 0; t < 3; ++t) {
                int j = 8 * t + wave;
                if (j < NT) {
                    bf16x8 bfr = *(const bf16x8*)&WaT[(j * 16 + lm) * K2 + ks * 32 + q * 8];
                    #pragma unroll
                    for (int mt = 0; mt < 2; ++mt)
                        acc2[t][mt] = __builtin_amdgcn_mfma_f32_16x16x32_bf16(af[mt], bfr, acc2[t][mt], 0, 0, 0);
                }
            }
        }
        #pragma unroll
        for (int t = 0; t < 3; ++t) {
            int j = 8 * t + wave;
            int n = j * 16 + lm;
            bool ok = (j < NT) && (n < HD);
            float bav = ok ? ba[n] : 0.f;
            float s = 0.f;
            #pragma unroll
            for (int mt = 0; mt < 2; ++mt)
                #pragma unroll
                for (int r = 0; r < 4; ++r) {
                    float hv = acc2[t][mt][r] + bav;
                    s += (hv > 0.f ? hv : 0.f);
                }
            s += __shfl_xor(s, 16);
            s += __shfl_xor(s, 32);
            if (ok && q == 0) Ar1[g * 512 + n] = f2bf(s * 0.03125f);
        }
    }
}

// ---------- generic LDS-free readout GEMM: C = [relu](A @ Bt^T + bias) ----------
template<int RELU, int OUTBF16>
__global__ __launch_bounds__(256, 4) void gemm_ro(
    const u16* __restrict__ A, const u16* __restrict__ Bt, const float* __restrict__ bias,
    const int KP, const int Nreal, const int outPitch, void* __restrict__ outp, const int nsteps)
{
    const int tid = threadIdx.x;
    const int wv = tid >> 6, lane = tid & 63, lm = lane & 15, q = lane >> 4;
    const int row0 = blockIdx.x * 64;
    const int col = blockIdx.y * 64 + wv * 16 + lm;
    f32x4 acc[4];
    #pragma unroll
    for (int mt = 0; mt < 4; ++mt) acc[mt] = (f32x4){0.f, 0.f, 0.f, 0.f};
    const u16* bp = Bt + col * KP + q * 8;
    const u16* ap = A + (row0 + lm) * KP + q * 8;
    for (int ks = 0; ks < nsteps; ++ks) {
        bf16x8 bfr = *(const bf16x8*)(bp + ks * 32);
        #pragma unroll
        for (int mt = 0; mt < 4; ++mt) {
            bf16x8 afr = *(const bf16x8*)(ap + mt * 16 * KP + ks * 32);
            acc[mt] = __builtin_amdgcn_mfma_f32_16x16x32_bf16(afr, bfr, acc[mt], 0, 0, 0);
        }
    }
    const float bv = (col < Nreal) ? bias[col] : 0.f;
    #pragma unroll
    for (int mt = 0; mt < 4; ++mt) {
        #pragma unroll
        for (int r = 0; r < 4; ++r) {
            int row = row0 + mt * 16 + q * 4 + r;
            float val = acc[mt][r] + bv;
            if (RELU) val = val > 0.f ? val : 0.f;
            if (OUTBF16) {
                ((u16*)outp)[row * outPitch + col] = (col < Nreal) ? f2bf(val) : (u16)0;
            } else {
                if (col < Nreal) ((float*)outp)[row * outPitch + col] = val;
            }
        }
    }
}

extern "C" void kernel_launch(void* const* d_in, const int* in_sizes, int n_in,
                              void* d_out, int out_size, void* d_ws, size_t ws_size,
                              hipStream_t stream) {
    (void)in_sizes; (void)n_in; (void)out_size; (void)ws_size;
    const float* v   = (const float*)d_in[0];
    const float* e   = (const float*)d_in[1];
    const float* glb = (const float*)d_in[2];
    const float* Wi  = (const float*)d_in[3];
    const float* bi  = (const float*)d_in[4];
    const float* Wm  = (const float*)d_in[5];
    const float* bm  = (const float*)d_in[6];
    const float* Wa  = (const float*)d_in[7];
    const float* ba  = (const float*)d_in[8];
    const float* Wr1 = (const float*)d_in[9];
    const float* br1 = (const float*)d_in[10];
    const float* Wr2 = (const float*)d_in[11];
    const float* br2 = (const float*)d_in[12];
    const float* Wr3 = (const float*)d_in[13];
    const float* br3 = (const float*)d_in[14];
    const int* src = (const int*)d_in[15];
    const int* dst = (const int*)d_in[16];

    char* ws = (char*)d_ws;
    u16* WiT  = (u16*)(ws + 0);            // 304*160*2  =   97280
    u16* WmT  = (u16*)(ws + 97280);        // 304*320*2  =  194560
    u16* WaT  = (u16*)(ws + 291840);       // 304*448*2  =  272384
    u16* Wr1T = (u16*)(ws + 564224);       // 576*512*2  =  589824
    u16* Wr2T = (u16*)(ws + 1154048);      // 384*576*2  =  442368
    u16* Wr3T = (u16*)(ws + 1596416);      //  64*384*2  =   49152
    u16* Ar1  = (u16*)(ws + 1645568);      // 4096*512*2 = 4194304
    u16* Ar2  = (u16*)(ws + 5839872);      // 4096*576*2 = 4718592
    u16* Ar3  = (u16*)(ws + 10558464);     // 4096*384*2 = 3145728

    prep_w<<<190,  256, 0, stream>>>(Wi,  WiT,  147, 300, 160, 304, 0);
    prep_w<<<380,  256, 0, stream>>>(Wm,  WmT,  300, 300, 320, 304, 0);
    prep_w<<<532,  256, 0, stream>>>(Wa,  WaT,  433, 300, 448, 304, 1);
    prep_w<<<1152, 256, 0, stream>>>(Wr1, Wr1T, 500, 550, 512, 576, 0);
    prep_w<<<864,  256, 0, stream>>>(Wr2, Wr2T, 550, 378, 576, 384, 0);
    prep_w<<<96,   256, 0, stream>>>(Wr3, Wr3T, 378, 12,  384, 64,  0);
    prep_glob<<<3392, 256, 0, stream>>>(glb, Ar1);

    gnn_mega<<<4096, 512, 0, stream>>>(v, e, src, dst, WiT, WmT, WaT, bi, bm, ba, Ar1);

    gemm_ro<1, 1><<<dim3(64, 9), 256, 0, stream>>>(Ar1, Wr1T, br1, 512, 550, 576, Ar2, 16);
    gemm_ro<1, 1><<<dim3(64, 6), 256, 0, stream>>>(Ar2, Wr2T, br2, 576, 378, 384, Ar3, 18);
    gemm_ro<0, 0><<<dim3(64, 1), 256, 0, stream>>>(Ar3, Wr3T, br3, 384, 12, 12, d_out, 12);
}